// Round 11
// baseline (306.544 us; speedup 1.0000x reference)
//
#include <hip/hip_runtime.h>
#include <hip/hip_fp16.h>

constexpr int TPB = 256;
constexpr int SH = 9;          // bucket = 512 consecutive destinations
constexpr int BD = 1 << SH;    // 512 dests per bucket (max 512 buckets -> n <= 262144)
constexpr int CHUNK = 4096;    // edges per binning block

typedef _Float16 half8 __attribute__((ext_vector_type(8)));
typedef float float4v __attribute__((ext_vector_type(4)));

__device__ __forceinline__ int wave_incl_scan(int x, int lane) {
#pragma unroll
  for (int d = 1; d < 64; d <<= 1) {
    int y = __shfl_up(x, d);
    if (lane >= d) x += y;
  }
  return x;
}

// ---------------- binned CSR build (grouped by destination) ----------------
// Buckets have fixed capacity `cap` (mean + 25%, >25-sigma for uniform-random
// edges): bucket b occupies [b*cap, b*cap+count) -> no global scan needed.

__global__ void bin_kernel(const int* __restrict__ row, const int* __restrict__ col,
                           int* __restrict__ bcur, int2* __restrict__ binned,
                           int e, int nb, int cap) {
  __shared__ int h[512];
  __shared__ int base[512];
  for (int i = threadIdx.x; i < nb; i += TPB) h[i] = 0;
  __syncthreads();
  int cb = blockIdx.x * CHUNK;
  int lim = min(cb + CHUNK, e);
  for (int i = cb + threadIdx.x; i < lim; i += TPB)
    atomicAdd(&h[col[i] >> SH], 1);
  __syncthreads();
  for (int i = threadIdx.x; i < nb; i += TPB) {
    int c = h[i];
    base[i] = c ? (i * cap + atomicAdd(&bcur[i], c)) : 0;
    h[i] = 0;  // reuse as local cursor
  }
  __syncthreads();
  for (int i = cb + threadIdx.x; i < lim; i += TPB) {
    int c = col[i];  // L2-hot re-read of this block's own chunk
    int b = c >> SH;
    int p = base[b] + atomicAdd(&h[b], 1);
    binned[p] = make_int2(row[i], c);
  }
}

// per bucket: fine counts -> scan -> offs2/dinv -> place (fused; binned stays L2-hot)
__global__ __launch_bounds__(512) void count_place_kernel(
    const int2* __restrict__ binned, const int* __restrict__ bcnt, int cap,
    int2* __restrict__ offs2, float* __restrict__ dinv, int* __restrict__ csr, int n) {
  __shared__ int cnt[BD];
  __shared__ int wsum[8];
  int t = threadIdx.x, lane = t & 63, wv = t >> 6;
  int b = blockIdx.x;
  int c0 = b << SH;
  int ndst = min(BD, n - c0);
  cnt[t] = 0;
  __syncthreads();
  int beg = b * cap;
  int end = beg + bcnt[b];
  for (int i = beg + t; i < end; i += 512)
    atomicAdd(&cnt[binned[i].y - c0], 1);
  __syncthreads();
  int v = cnt[t];
  int ps = wave_incl_scan(v, lane);
  if (lane == 63) wsum[wv] = ps;
  __syncthreads();
  int woff = 0;
#pragma unroll
  for (int w = 0; w < 8; w++) woff += (w < wv) ? wsum[w] : 0;
  int ex = woff + ps - v;
  if (t < ndst) {
    offs2[c0 + t] = make_int2(beg + ex, beg + ex + v);
    dinv[c0 + t] = rsqrtf(1.0f + (float)v);  // deg = incoming + self-loop
  }
  __syncthreads();  // counts consumed; reuse cnt[] as cursors
  cnt[t] = beg + ex;
  __syncthreads();
  for (int i = beg + t; i < end; i += 512) {
    int2 rc = binned[i];
    int p = atomicAdd(&cnt[rc.y - c0], 1);
    csr[p] = rc.x;
  }
}

// ---------------- MFMA GEMM (fp16 in, fp32 acc; no LDS) ----------------

// Pack W[K,M] fp32 into B-fragment order for mfma_f32_16x16x32_f16:
// frag f = ct*KT+kt; lane holds B[k=kt*32+(lane>>4)*8+j][n=ct*16+(lane&15)].
template <int K, int M, int CT, int KT>
__global__ void pack_w_kernel(const float* __restrict__ W, _Float16* __restrict__ P) {
  int idx = blockIdx.x * TPB + threadIdx.x;
  if (idx >= CT * KT * 64 * 8) return;
  int j = idx & 7;
  int lane = (idx >> 3) & 63;
  int f = idx >> 9;
  int kt = f % KT, ct = f / KT;
  int c = ct * 16 + (lane & 15);
  int k = kt * 32 + (lane >> 4) * 8 + j;
  float v = (c < M) ? W[k * M + c] : 0.f;
  P[idx] = (_Float16)v;
}

// layer-1: fp32 x[n,K] -> fp16 out[n,M], rows pre-scaled by dinv[r].
// 4 waves/block, 16 rows/wave.
template <int K, int M, int CT>
__global__ __launch_bounds__(256) void gemm_mfma_f32in(const float* __restrict__ x,
                                                       const _Float16* __restrict__ PW,
                                                       const float* __restrict__ dinv,
                                                       _Float16* __restrict__ out, int n) {
  constexpr int KT = K / 32;
  int lane = threadIdx.x & 63, wv = threadIdx.x >> 6;
  int m = lane & 15, q = lane >> 4;
  int row0w = blockIdx.x * 64 + wv * 16;
  int arow = row0w + m;
  int ar = arow < n ? arow : n - 1;  // clamp; stores are guarded
  const half8* pw = (const half8*)PW;

  float4v acc[CT];
#pragma unroll
  for (int ct = 0; ct < CT; ct++) acc[ct] = (float4v){0.f, 0.f, 0.f, 0.f};

#pragma unroll
  for (int kt = 0; kt < KT; kt++) {
    const float* xp = x + (size_t)ar * K + kt * 32 + q * 8;
    float4 x0 = *(const float4*)xp;
    float4 x1 = *(const float4*)(xp + 4);
    half8 a;
    a[0] = (_Float16)x0.x; a[1] = (_Float16)x0.y;
    a[2] = (_Float16)x0.z; a[3] = (_Float16)x0.w;
    a[4] = (_Float16)x1.x; a[5] = (_Float16)x1.y;
    a[6] = (_Float16)x1.z; a[7] = (_Float16)x1.w;
#pragma unroll
    for (int ct = 0; ct < CT; ct++) {
      half8 b = pw[(ct * KT + kt) * 64 + lane];
      acc[ct] = __builtin_amdgcn_mfma_f32_16x16x32_f16(a, b, acc[ct], 0, 0, 0);
    }
  }
  // D layout: col = lane&15, row = q*4 + reg
  int r0 = row0w + q * 4;
  float dreg[4];
#pragma unroll
  for (int reg = 0; reg < 4; reg++) {
    int r = r0 + reg;
    dreg[reg] = (r < n) ? dinv[r] : 0.f;
  }
#pragma unroll
  for (int ct = 0; ct < CT; ct++) {
    int c = ct * 16 + m;
    if (c < M) {
#pragma unroll
      for (int reg = 0; reg < 4; reg++) {
        int r = r0 + reg;
        if (r < n) out[(size_t)r * M + c] = (_Float16)(acc[ct][reg] * dreg[reg]);
      }
    }
  }
}

// layer-2: fp16 x[n,K] -> fp16 out[n,M]  (input rows pre-scaled -> output
// rows come out pre-scaled automatically by linearity)
template <int K, int M, int CT>
__global__ __launch_bounds__(256) void gemm_mfma_f16in(const _Float16* __restrict__ x,
                                                       const _Float16* __restrict__ PW,
                                                       _Float16* __restrict__ out, int n) {
  constexpr int KT = K / 32;
  int lane = threadIdx.x & 63, wv = threadIdx.x >> 6;
  int m = lane & 15, q = lane >> 4;
  int row0w = blockIdx.x * 64 + wv * 16;
  int arow = row0w + m;
  int ar = arow < n ? arow : n - 1;
  const half8* pw = (const half8*)PW;

  float4v acc[CT];
#pragma unroll
  for (int ct = 0; ct < CT; ct++) acc[ct] = (float4v){0.f, 0.f, 0.f, 0.f};

#pragma unroll
  for (int kt = 0; kt < KT; kt++) {
    half8 a = *(const half8*)(x + (size_t)ar * K + kt * 32 + q * 8);
#pragma unroll
    for (int ct = 0; ct < CT; ct++) {
      half8 b = pw[(ct * KT + kt) * 64 + lane];
      acc[ct] = __builtin_amdgcn_mfma_f32_16x16x32_f16(a, b, acc[ct], 0, 0, 0);
    }
  }
  int r0 = row0w + q * 4;
#pragma unroll
  for (int ct = 0; ct < CT; ct++) {
    int c = ct * 16 + m;
    if (c < M) {
#pragma unroll
      for (int reg = 0; reg < 4; reg++) {
        int r = r0 + reg;
        if (r < n) out[(size_t)r * M + c] = (_Float16)acc[ct][reg];
      }
    }
  }
}

// layer-3: fp16 x[n,K] -> fp32 out[n,M] with fused bias (no relu)
template <int K, int M, int CT>
__global__ __launch_bounds__(256) void gemm_mfma_f16in_f32out(
    const _Float16* __restrict__ x, const _Float16* __restrict__ PW,
    const float* __restrict__ bias, float* __restrict__ out, int n) {
  constexpr int KT = K / 32;
  int lane = threadIdx.x & 63, wv = threadIdx.x >> 6;
  int m = lane & 15, q = lane >> 4;
  int row0w = blockIdx.x * 64 + wv * 16;
  int arow = row0w + m;
  int ar = arow < n ? arow : n - 1;
  const half8* pw = (const half8*)PW;

  float4v acc[CT];
#pragma unroll
  for (int ct = 0; ct < CT; ct++) acc[ct] = (float4v){0.f, 0.f, 0.f, 0.f};

#pragma unroll
  for (int kt = 0; kt < KT; kt++) {
    half8 a = *(const half8*)(x + (size_t)ar * K + kt * 32 + q * 8);
#pragma unroll
    for (int ct = 0; ct < CT; ct++) {
      half8 b = pw[(ct * KT + kt) * 64 + lane];
      acc[ct] = __builtin_amdgcn_mfma_f32_16x16x32_f16(a, b, acc[ct], 0, 0, 0);
    }
  }
  int r0 = row0w + q * 4;
#pragma unroll
  for (int ct = 0; ct < CT; ct++) {
    int c = ct * 16 + m;
    if (c < M) {
      float bb = bias[c];
#pragma unroll
      for (int reg = 0; reg < 4; reg++) {
        int r = r0 + reg;
        if (r < n) out[(size_t)r * M + c] = acc[ct][reg] + bb;
      }
    }
  }
}

// ---------------- Aggregation: pre-scaled features, unit edge weights ----------------

__device__ __forceinline__ void h4_add(uint2 u, float4& acc) {
  __half2 h0 = *(__half2*)&u.x, h1 = *(__half2*)&u.y;
  float2 f0 = __half22float2(h0), f1 = __half22float2(h1);
  acc.x += f0.x; acc.y += f0.y; acc.z += f1.x; acc.w += f1.y;
}

// Slot (16 lanes) owns one node; 4 nodes/wave. Input rows are pre-scaled by
// dinv[src] so every edge has weight 1: per batch = 1 coalesced csr load
// (64B/slot) + up to 16 independent 128B row-gathers + pure adds.
// RELU_BIAS=true (layers 1/2): out = relu(acc*di + b)*di (pre-scaled for next gemm).
// RELU_BIAS=false (layer-3 pre-agg): out = acc*di (= L(h2), unscaled).
template <bool RELU_BIAS>
__global__ __launch_bounds__(256) void agg64_kernel(
    const uint2* __restrict__ xw2, const float* __restrict__ dinv,
    const int* __restrict__ csr, const int2* __restrict__ offs2,
    const float* __restrict__ bias, uint2* __restrict__ out2, int n) {
  int lane = threadIdx.x & 63, wv = threadIdx.x >> 6;
  int slot = lane >> 4, fl = lane & 15;
  int sb = slot << 4;  // slot's base lane
  int i = blockIdx.x * 16 + wv * 4 + slot;
  bool valid = i < n;
  int ic = valid ? i : n - 1;
  int2 oe = offs2[ic];
  int beg = oe.x;
  int end = valid ? oe.y : beg;
  float di = dinv[ic];
  float4 acc = {0.f, 0.f, 0.f, 0.f};
  h4_add(xw2[(size_t)ic * 16 + fl], acc);  // self-loop (input pre-scaled)

  for (int b = beg; b < end; b += 16) {
    int idx = b + fl;
    int rr = 0;
    if (idx < end) rr = csr[idx];  // csr slack holds poison; predicate
    int cnt = end - b;             // slot-uniform
    uint2 u[16];
#pragma unroll
    for (int j = 0; j < 16; j++) {
      if (j < cnt) {
        int r = __shfl(rr, sb + j);
        u[j] = xw2[(size_t)r * 16 + fl];
      }
    }
#pragma unroll
    for (int j = 0; j < 16; j++) {
      if (j < cnt) h4_add(u[j], acc);
    }
  }

  if (valid) {
    float4 o;
    if (RELU_BIAS) {
      const float4* b4 = (const float4*)bias;
      float4 bb = b4[fl];
      o.x = fmaxf(acc.x * di + bb.x, 0.f) * di;
      o.y = fmaxf(acc.y * di + bb.y, 0.f) * di;
      o.z = fmaxf(acc.z * di + bb.z, 0.f) * di;
      o.w = fmaxf(acc.w * di + bb.w, 0.f) * di;
    } else {
      o.x = acc.x * di; o.y = acc.y * di;
      o.z = acc.z * di; o.w = acc.w * di;
    }
    __half2 h0 = __float22half2_rn(make_float2(o.x, o.y));
    __half2 h1 = __float22half2_rn(make_float2(o.z, o.w));
    uint2 u;
    u.x = *(unsigned*)&h0;
    u.y = *(unsigned*)&h1;
    out2[(size_t)i * 16 + fl] = u;
  }
}

// ---------------- launcher ----------------

extern "C" void kernel_launch(void* const* d_in, const int* in_sizes, int n_in,
                              void* d_out, int out_size, void* d_ws, size_t ws_size,
                              hipStream_t stream) {
  const float* x  = (const float*)d_in[0];
  const int*   ei = (const int*)d_in[1];
  const float* W1 = (const float*)d_in[2];
  const float* b1 = (const float*)d_in[3];
  const float* W2 = (const float*)d_in[4];
  const float* b2 = (const float*)d_in[5];
  const float* W3 = (const float*)d_in[6];
  const float* b3 = (const float*)d_in[7];

  int n = in_sizes[0] / 128;
  int e = in_sizes[1] / 2;
  const int* rowA = ei;      // edge_index[0] = source
  const int* colA = ei + e;  // edge_index[1] = destination (segment id)

  int nb = (n + BD - 1) >> SH;  // buckets (<= 512)
  int meanb = e / nb;
  int cap = meanb + (meanb / 4 > 1024 ? meanb / 4 : 1024);  // >25 sigma slack
  int nch = (e + CHUNK - 1) / CHUNK;

  size_t off = 0;
  auto alloc = [&](size_t bytes) {
    void* p = (char*)d_ws + off;
    off += (bytes + 255) & ~(size_t)255;
    return p;
  };
  // bufA (n*64*4 B) also aliases the binned edge array (nb*cap*8 <= n*205 B)
  __half* bufA  = (__half*)alloc((size_t)n * 64 * 4);
  __half* bufB  = (__half*)alloc((size_t)n * 64 * 4);
  int2*  offs2  = (int2*)alloc((size_t)n * 8);
  float* dinv   = (float*)alloc((size_t)n * 4);
  int*   csr    = (int*)alloc((size_t)nb * cap * 4);
  int*   bcur   = (int*)alloc(512 * 4);
  _Float16* PW1 = (_Float16*)alloc(4 * 4 * 64 * 8 * 2);  // CT=4, KT=4
  _Float16* PW2 = (_Float16*)alloc(4 * 2 * 64 * 8 * 2);  // CT=4, KT=2
  _Float16* PW3 = (_Float16*)alloc(3 * 2 * 64 * 8 * 2);  // CT=3, KT=2
  int2*  binned = (int2*)bufA;  // consumed by count_place before gemm1 writes bufA
  (void)ws_size; (void)n_in; (void)out_size;

  hipMemsetAsync(bcur, 0, (size_t)nb * 4, stream);
  bin_kernel<<<nch, TPB, 0, stream>>>(rowA, colA, bcur, binned, e, nb, cap);
  count_place_kernel<<<nb, 512, 0, stream>>>(binned, bcur, cap, offs2, dinv, csr, n);

  pack_w_kernel<128, 64, 4, 4><<<(4 * 4 * 512 + TPB - 1) / TPB, TPB, 0, stream>>>(W1, PW1);
  pack_w_kernel<64, 64, 4, 2><<<(4 * 2 * 512 + TPB - 1) / TPB, TPB, 0, stream>>>(W2, PW2);
  pack_w_kernel<64, 40, 3, 2><<<(3 * 2 * 512 + TPB - 1) / TPB, TPB, 0, stream>>>(W3, PW3);

  int gmf = (n + 63) / 64;   // 4 waves/block, 16 rows/wave
  int gagg = (n + 15) / 16;  // 4 nodes per wave, 4 waves/block
  gemm_mfma_f32in<128, 64, 4><<<gmf, TPB, 0, stream>>>(x, PW1, dinv, (_Float16*)bufA, n);
  agg64_kernel<true><<<gagg, TPB, 0, stream>>>((const uint2*)bufA, dinv, csr, offs2,
                                               b1, (uint2*)bufB, n);
  gemm_mfma_f16in<64, 64, 4><<<gmf, TPB, 0, stream>>>((const _Float16*)bufB, PW2,
                                                      (_Float16*)bufA, n);
  agg64_kernel<true><<<gagg, TPB, 0, stream>>>((const uint2*)bufA, dinv, csr, offs2,
                                               b2, (uint2*)bufB, n);
  // layer 3: aggregate-first (L(h2)), then GEMM with fused bias -> fp32 d_out
  agg64_kernel<false><<<gagg, TPB, 0, stream>>>((const uint2*)bufB, dinv, csr, offs2,
                                                nullptr, (uint2*)bufA, n);
  gemm_mfma_f16in_f32out<64, 40, 3><<<gmf, TPB, 0, stream>>>((const _Float16*)bufA, PW3,
                                                             b3, (float*)d_out, n);
}

// Round 12
// 297.887 us; speedup vs baseline: 1.0291x; 1.0291x over previous
//
#include <hip/hip_runtime.h>
#include <hip/hip_fp16.h>

constexpr int TPB = 256;
constexpr int SH = 9;          // bucket = 512 consecutive destinations
constexpr int BD = 1 << SH;    // 512 dests per bucket (max 512 buckets -> n <= 262144)
constexpr int CHUNK = 4096;    // edges per binning block

typedef _Float16 half8 __attribute__((ext_vector_type(8)));
typedef float float4v __attribute__((ext_vector_type(4)));

__device__ __forceinline__ int wave_incl_scan(int x, int lane) {
#pragma unroll
  for (int d = 1; d < 64; d <<= 1) {
    int y = __shfl_up(x, d);
    if (lane >= d) x += y;
  }
  return x;
}

// ---------------- binned CSR build (grouped by destination) ----------------
// Buckets have fixed capacity `cap` (mean + 25%, >25-sigma for uniform-random
// edges): bucket b occupies [b*cap, b*cap+count) -> no global scan needed.

__global__ void bin_kernel(const int* __restrict__ row, const int* __restrict__ col,
                           int* __restrict__ bcur, int2* __restrict__ binned,
                           int e, int nb, int cap) {
  __shared__ int h[512];
  __shared__ int base[512];
  for (int i = threadIdx.x; i < nb; i += TPB) h[i] = 0;
  __syncthreads();
  int cb = blockIdx.x * CHUNK;
  int lim = min(cb + CHUNK, e);
  for (int i = cb + threadIdx.x; i < lim; i += TPB)
    atomicAdd(&h[col[i] >> SH], 1);
  __syncthreads();
  for (int i = threadIdx.x; i < nb; i += TPB) {
    int c = h[i];
    base[i] = c ? (i * cap + atomicAdd(&bcur[i], c)) : 0;
    h[i] = 0;  // reuse as local cursor
  }
  __syncthreads();
  for (int i = cb + threadIdx.x; i < lim; i += TPB) {
    int c = col[i];  // L2-hot re-read of this block's own chunk
    int b = c >> SH;
    int p = base[b] + atomicAdd(&h[b], 1);
    binned[p] = make_int2(row[i], c);
  }
}

// per bucket: fine counts -> scan -> offs2/dinv -> place (fused; binned stays L2-hot)
__global__ __launch_bounds__(512) void count_place_kernel(
    const int2* __restrict__ binned, const int* __restrict__ bcnt, int cap,
    int2* __restrict__ offs2, float* __restrict__ dinv, int* __restrict__ csr, int n) {
  __shared__ int cnt[BD];
  __shared__ int wsum[8];
  int t = threadIdx.x, lane = t & 63, wv = t >> 6;
  int b = blockIdx.x;
  int c0 = b << SH;
  int ndst = min(BD, n - c0);
  cnt[t] = 0;
  __syncthreads();
  int beg = b * cap;
  int end = beg + bcnt[b];
  for (int i = beg + t; i < end; i += 512)
    atomicAdd(&cnt[binned[i].y - c0], 1);
  __syncthreads();
  int v = cnt[t];
  int ps = wave_incl_scan(v, lane);
  if (lane == 63) wsum[wv] = ps;
  __syncthreads();
  int woff = 0;
#pragma unroll
  for (int w = 0; w < 8; w++) woff += (w < wv) ? wsum[w] : 0;
  int ex = woff + ps - v;
  if (t < ndst) {
    offs2[c0 + t] = make_int2(beg + ex, beg + ex + v);
    dinv[c0 + t] = rsqrtf(1.0f + (float)v);  // deg = incoming + self-loop
  }
  __syncthreads();  // counts consumed; reuse cnt[] as cursors
  cnt[t] = beg + ex;
  __syncthreads();
  for (int i = beg + t; i < end; i += 512) {
    int2 rc = binned[i];
    int p = atomicAdd(&cnt[rc.y - c0], 1);
    csr[p] = rc.x;
  }
}

// ---------------- MFMA GEMM (fp16 in, fp32 acc; no LDS) ----------------

// Pack W[K,M] fp32 into B-fragment order for mfma_f32_16x16x32_f16:
// frag f = ct*KT+kt; lane holds B[k=kt*32+(lane>>4)*8+j][n=ct*16+(lane&15)].
template <int K, int M, int CT, int KT>
__global__ void pack_w_kernel(const float* __restrict__ W, _Float16* __restrict__ P) {
  int idx = blockIdx.x * TPB + threadIdx.x;
  if (idx >= CT * KT * 64 * 8) return;
  int j = idx & 7;
  int lane = (idx >> 3) & 63;
  int f = idx >> 9;
  int kt = f % KT, ct = f / KT;
  int c = ct * 16 + (lane & 15);
  int k = kt * 32 + (lane >> 4) * 8 + j;
  float v = (c < M) ? W[k * M + c] : 0.f;
  P[idx] = (_Float16)v;
}

// layer-1: fp32 x[n,K] -> fp16 out[n,M], rows pre-scaled by dinv[r].
template <int K, int M, int CT>
__global__ __launch_bounds__(256) void gemm_mfma_f32in(const float* __restrict__ x,
                                                       const _Float16* __restrict__ PW,
                                                       const float* __restrict__ dinv,
                                                       _Float16* __restrict__ out, int n) {
  constexpr int KT = K / 32;
  int lane = threadIdx.x & 63, wv = threadIdx.x >> 6;
  int m = lane & 15, q = lane >> 4;
  int row0w = blockIdx.x * 64 + wv * 16;
  int arow = row0w + m;
  int ar = arow < n ? arow : n - 1;  // clamp; stores are guarded
  const half8* pw = (const half8*)PW;

  float4v acc[CT];
#pragma unroll
  for (int ct = 0; ct < CT; ct++) acc[ct] = (float4v){0.f, 0.f, 0.f, 0.f};

#pragma unroll
  for (int kt = 0; kt < KT; kt++) {
    const float* xp = x + (size_t)ar * K + kt * 32 + q * 8;
    float4 x0 = *(const float4*)xp;
    float4 x1 = *(const float4*)(xp + 4);
    half8 a;
    a[0] = (_Float16)x0.x; a[1] = (_Float16)x0.y;
    a[2] = (_Float16)x0.z; a[3] = (_Float16)x0.w;
    a[4] = (_Float16)x1.x; a[5] = (_Float16)x1.y;
    a[6] = (_Float16)x1.z; a[7] = (_Float16)x1.w;
#pragma unroll
    for (int ct = 0; ct < CT; ct++) {
      half8 b = pw[(ct * KT + kt) * 64 + lane];
      acc[ct] = __builtin_amdgcn_mfma_f32_16x16x32_f16(a, b, acc[ct], 0, 0, 0);
    }
  }
  // D layout: col = lane&15, row = q*4 + reg
  int r0 = row0w + q * 4;
  float dreg[4];
#pragma unroll
  for (int reg = 0; reg < 4; reg++) {
    int r = r0 + reg;
    dreg[reg] = (r < n) ? dinv[r] : 0.f;
  }
#pragma unroll
  for (int ct = 0; ct < CT; ct++) {
    int c = ct * 16 + m;
    if (c < M) {
#pragma unroll
      for (int reg = 0; reg < 4; reg++) {
        int r = r0 + reg;
        if (r < n) out[(size_t)r * M + c] = (_Float16)(acc[ct][reg] * dreg[reg]);
      }
    }
  }
}

// layer-2: fp16 x[n,K] -> fp16 out[n,M]  (rows stay pre-scaled by linearity)
template <int K, int M, int CT>
__global__ __launch_bounds__(256) void gemm_mfma_f16in(const _Float16* __restrict__ x,
                                                       const _Float16* __restrict__ PW,
                                                       _Float16* __restrict__ out, int n) {
  constexpr int KT = K / 32;
  int lane = threadIdx.x & 63, wv = threadIdx.x >> 6;
  int m = lane & 15, q = lane >> 4;
  int row0w = blockIdx.x * 64 + wv * 16;
  int arow = row0w + m;
  int ar = arow < n ? arow : n - 1;
  const half8* pw = (const half8*)PW;

  float4v acc[CT];
#pragma unroll
  for (int ct = 0; ct < CT; ct++) acc[ct] = (float4v){0.f, 0.f, 0.f, 0.f};

#pragma unroll
  for (int kt = 0; kt < KT; kt++) {
    half8 a = *(const half8*)(x + (size_t)ar * K + kt * 32 + q * 8);
#pragma unroll
    for (int ct = 0; ct < CT; ct++) {
      half8 b = pw[(ct * KT + kt) * 64 + lane];
      acc[ct] = __builtin_amdgcn_mfma_f32_16x16x32_f16(a, b, acc[ct], 0, 0, 0);
    }
  }
  int r0 = row0w + q * 4;
#pragma unroll
  for (int ct = 0; ct < CT; ct++) {
    int c = ct * 16 + m;
    if (c < M) {
#pragma unroll
      for (int reg = 0; reg < 4; reg++) {
        int r = r0 + reg;
        if (r < n) out[(size_t)r * M + c] = (_Float16)acc[ct][reg];
      }
    }
  }
}

// layer-3: fp16 x[n,K] -> fp32 out[n,M] with fused bias (no relu)
template <int K, int M, int CT>
__global__ __launch_bounds__(256) void gemm_mfma_f16in_f32out(
    const _Float16* __restrict__ x, const _Float16* __restrict__ PW,
    const float* __restrict__ bias, float* __restrict__ out, int n) {
  constexpr int KT = K / 32;
  int lane = threadIdx.x & 63, wv = threadIdx.x >> 6;
  int m = lane & 15, q = lane >> 4;
  int row0w = blockIdx.x * 64 + wv * 16;
  int arow = row0w + m;
  int ar = arow < n ? arow : n - 1;
  const half8* pw = (const half8*)PW;

  float4v acc[CT];
#pragma unroll
  for (int ct = 0; ct < CT; ct++) acc[ct] = (float4v){0.f, 0.f, 0.f, 0.f};

#pragma unroll
  for (int kt = 0; kt < KT; kt++) {
    half8 a = *(const half8*)(x + (size_t)ar * K + kt * 32 + q * 8);
#pragma unroll
    for (int ct = 0; ct < CT; ct++) {
      half8 b = pw[(ct * KT + kt) * 64 + lane];
      acc[ct] = __builtin_amdgcn_mfma_f32_16x16x32_f16(a, b, acc[ct], 0, 0, 0);
    }
  }
  int r0 = row0w + q * 4;
#pragma unroll
  for (int ct = 0; ct < CT; ct++) {
    int c = ct * 16 + m;
    if (c < M) {
      float bb = bias[c];
#pragma unroll
      for (int reg = 0; reg < 4; reg++) {
        int r = r0 + reg;
        if (r < n) out[(size_t)r * M + c] = acc[ct][reg] + bb;
      }
    }
  }
}

// ---------------- Aggregation: pre-scaled features, unit edge weights ----------------

__device__ __forceinline__ void h4_add(uint2 u, float4& acc) {
  __half2 h0 = *(__half2*)&u.x, h1 = *(__half2*)&u.y;
  float2 f0 = __half22float2(h0), f1 = __half22float2(h1);
  acc.x += f0.x; acc.y += f0.y; acc.z += f1.x; acc.w += f1.y;
}

// Slot (16 lanes) owns one node; 4 nodes/wave. Rows pre-scaled by dinv[src] so
// edges have weight 1. Full 16-edge batches are UNCONDITIONAL (u[16] live ->
// 16 outstanding 128B gathers) with next batch's csr word prefetched across
// the add chain; one guarded tail batch.
template <bool RELU_BIAS>
__global__ __launch_bounds__(256) void agg64_kernel(
    const uint2* __restrict__ xw2, const float* __restrict__ dinv,
    const int* __restrict__ csr, const int2* __restrict__ offs2,
    const float* __restrict__ bias, uint2* __restrict__ out2, int n) {
  int lane = threadIdx.x & 63, wv = threadIdx.x >> 6;
  int slot = lane >> 4, fl = lane & 15;
  int sb = slot << 4;  // slot's base lane
  int i = blockIdx.x * 16 + wv * 4 + slot;
  bool valid = i < n;
  int ic = valid ? i : n - 1;
  int2 oe = offs2[ic];
  int beg = oe.x;
  int end = valid ? oe.y : beg;
  float di = dinv[ic];
  float4 acc = {0.f, 0.f, 0.f, 0.f};
  h4_add(xw2[(size_t)ic * 16 + fl], acc);  // self-loop (input pre-scaled)

  int b = beg;
  int endf = beg + ((end - beg) & ~15);  // full-batch limit
  int rr = (b < endf) ? csr[b + fl] : 0;
  while (b < endf) {
    int rr_cur = rr;
    b += 16;
    if (b < endf) rr = csr[b + fl];  // prefetch next batch across this one
    uint2 u[16];
#pragma unroll
    for (int j = 0; j < 16; j++) {
      int r = __shfl(rr_cur, sb + j);
      u[j] = xw2[(size_t)r * 16 + fl];  // unconditional: all 16 in flight
    }
#pragma unroll
    for (int j = 0; j < 16; j++) h4_add(u[j], acc);
  }
  // tail (< 16 edges)
  if (b < end) {
    int idx = b + fl;
    int rt = (idx < end) ? csr[idx] : 0;
    int cnt = end - b;
    uint2 u[16];
#pragma unroll
    for (int j = 0; j < 16; j++) {
      if (j < cnt) {
        int r = __shfl(rt, sb + j);
        u[j] = xw2[(size_t)r * 16 + fl];
      }
    }
#pragma unroll
    for (int j = 0; j < 16; j++) {
      if (j < cnt) h4_add(u[j], acc);
    }
  }

  if (valid) {
    float4 o;
    if (RELU_BIAS) {
      const float4* b4 = (const float4*)bias;
      float4 bb = b4[fl];
      o.x = fmaxf(acc.x * di + bb.x, 0.f) * di;
      o.y = fmaxf(acc.y * di + bb.y, 0.f) * di;
      o.z = fmaxf(acc.z * di + bb.z, 0.f) * di;
      o.w = fmaxf(acc.w * di + bb.w, 0.f) * di;
    } else {
      o.x = acc.x * di; o.y = acc.y * di;
      o.z = acc.z * di; o.w = acc.w * di;
    }
    __half2 h0 = __float22half2_rn(make_float2(o.x, o.y));
    __half2 h1 = __float22half2_rn(make_float2(o.z, o.w));
    uint2 u;
    u.x = *(unsigned*)&h0;
    u.y = *(unsigned*)&h1;
    out2[(size_t)i * 16 + fl] = u;
  }
}

// ---------------- launcher ----------------

extern "C" void kernel_launch(void* const* d_in, const int* in_sizes, int n_in,
                              void* d_out, int out_size, void* d_ws, size_t ws_size,
                              hipStream_t stream) {
  const float* x  = (const float*)d_in[0];
  const int*   ei = (const int*)d_in[1];
  const float* W1 = (const float*)d_in[2];
  const float* b1 = (const float*)d_in[3];
  const float* W2 = (const float*)d_in[4];
  const float* b2 = (const float*)d_in[5];
  const float* W3 = (const float*)d_in[6];
  const float* b3 = (const float*)d_in[7];

  int n = in_sizes[0] / 128;
  int e = in_sizes[1] / 2;
  const int* rowA = ei;      // edge_index[0] = source
  const int* colA = ei + e;  // edge_index[1] = destination (segment id)

  int nb = (n + BD - 1) >> SH;  // buckets (<= 512)
  int meanb = e / nb;
  int cap = meanb + (meanb / 4 > 1024 ? meanb / 4 : 1024);  // >25 sigma slack
  int nch = (e + CHUNK - 1) / CHUNK;

  size_t off = 0;
  auto alloc = [&](size_t bytes) {
    void* p = (char*)d_ws + off;
    off += (bytes + 255) & ~(size_t)255;
    return p;
  };
  // bufA (n*64*4 B) also aliases the binned edge array (nb*cap*8 <= n*205 B)
  __half* bufA  = (__half*)alloc((size_t)n * 64 * 4);
  __half* bufB  = (__half*)alloc((size_t)n * 64 * 4);
  int2*  offs2  = (int2*)alloc((size_t)n * 8);
  float* dinv   = (float*)alloc((size_t)n * 4);
  int*   csr    = (int*)alloc((size_t)nb * cap * 4);
  int*   bcur   = (int*)alloc(512 * 4);
  _Float16* PW1 = (_Float16*)alloc(4 * 4 * 64 * 8 * 2);  // CT=4, KT=4
  _Float16* PW2 = (_Float16*)alloc(4 * 2 * 64 * 8 * 2);  // CT=4, KT=2
  _Float16* PW3 = (_Float16*)alloc(3 * 2 * 64 * 8 * 2);  // CT=3, KT=2
  int2*  binned = (int2*)bufA;  // consumed by count_place before gemm1 writes bufA
  (void)ws_size; (void)n_in; (void)out_size;

  hipMemsetAsync(bcur, 0, (size_t)nb * 4, stream);
  bin_kernel<<<nch, TPB, 0, stream>>>(rowA, colA, bcur, binned, e, nb, cap);
  count_place_kernel<<<nb, 512, 0, stream>>>(binned, bcur, cap, offs2, dinv, csr, n);

  pack_w_kernel<128, 64, 4, 4><<<(4 * 4 * 512 + TPB - 1) / TPB, TPB, 0, stream>>>(W1, PW1);
  pack_w_kernel<64, 64, 4, 2><<<(4 * 2 * 512 + TPB - 1) / TPB, TPB, 0, stream>>>(W2, PW2);
  pack_w_kernel<64, 40, 3, 2><<<(3 * 2 * 512 + TPB - 1) / TPB, TPB, 0, stream>>>(W3, PW3);

  int gmf = (n + 63) / 64;   // 4 waves/block, 16 rows/wave
  int gagg = (n + 15) / 16;  // 4 nodes per wave, 4 waves/block
  gemm_mfma_f32in<128, 64, 4><<<gmf, TPB, 0, stream>>>(x, PW1, dinv, (_Float16*)bufA, n);
  agg64_kernel<true><<<gagg, TPB, 0, stream>>>((const uint2*)bufA, dinv, csr, offs2,
                                               b1, (uint2*)bufB, n);
  gemm_mfma_f16in<64, 64, 4><<<gmf, TPB, 0, stream>>>((const _Float16*)bufB, PW2,
                                                      (_Float16*)bufA, n);
  agg64_kernel<true><<<gagg, TPB, 0, stream>>>((const uint2*)bufA, dinv, csr, offs2,
                                               b2, (uint2*)bufB, n);
  // layer 3: aggregate-first (L(h2)), then GEMM with fused bias -> fp32 d_out
  agg64_kernel<false><<<gagg, TPB, 0, stream>>>((const uint2*)bufB, dinv, csr, offs2,
                                                nullptr, (uint2*)bufA, n);
  gemm_mfma_f16in_f32out<64, 40, 3><<<gmf, TPB, 0, stream>>>((const _Float16*)bufA, PW3,
                                                             b3, (float*)d_out, n);
}